// Round 1
// baseline (536.100 us; speedup 1.0000x reference)
//
#include <hip/hip_runtime.h>

typedef unsigned long long u64;

#define DEVI __device__ __forceinline__

DEVI float gelu_f(float x) { return 0.5f * x * (1.0f + erff(x * 0.70710678f)); }

DEVI void ce64(u64& a, u64& b) { u64 lo = a < b ? a : b; u64 hi = a < b ? b : a; a = lo; b = hi; }

DEVI u64 shflx64(u64 v, int m) {
  unsigned lo = (unsigned)__shfl_xor((int)(v & 0xffffffffull), m, 64);
  unsigned hi = (unsigned)__shfl_xor((int)(v >> 32), m, 64);
  return ((u64)hi << 32) | lo;
}

// t, o both sorted ascending; t <- smallest 8 of union, sorted ascending.
DEVI void take8(u64 t[8], const u64 o[8]) {
  u64 s[8];
#pragma unroll
  for (int i = 0; i < 8; ++i) { u64 x = o[7 - i]; s[i] = (t[i] < x) ? t[i] : x; }
  ce64(s[0], s[4]); ce64(s[1], s[5]); ce64(s[2], s[6]); ce64(s[3], s[7]);
  ce64(s[0], s[2]); ce64(s[1], s[3]); ce64(s[4], s[6]); ce64(s[5], s[7]);
  ce64(s[0], s[1]); ce64(s[2], s[3]); ce64(s[4], s[5]); ce64(s[6], s[7]);
#pragma unroll
  for (int i = 0; i < 8; ++i) t[i] = s[i];
}

// ---------------- key norms ----------------
__global__ __launch_bounds__(256) void knorm_kernel(const float* __restrict__ keys,
                                                    float* __restrict__ knorm) {
  int j = blockIdx.x * 256 + threadIdx.x;
  if (j >= 100000) return;
  const float4* kp = (const float4*)(keys + (size_t)j * 64);
  float a0 = 0.f, a1 = 0.f, a2 = 0.f, a3 = 0.f;
#pragma unroll
  for (int u = 0; u < 16; u += 4) {
    float4 v0 = kp[u], v1 = kp[u + 1], v2 = kp[u + 2], v3 = kp[u + 3];
    a0 = fmaf(v0.x, v0.x, a0); a0 = fmaf(v0.y, v0.y, a0); a0 = fmaf(v0.z, v0.z, a0); a0 = fmaf(v0.w, v0.w, a0);
    a1 = fmaf(v1.x, v1.x, a1); a1 = fmaf(v1.y, v1.y, a1); a1 = fmaf(v1.z, v1.z, a1); a1 = fmaf(v1.w, v1.w, a1);
    a2 = fmaf(v2.x, v2.x, a2); a2 = fmaf(v2.y, v2.y, a2); a2 = fmaf(v2.z, v2.z, a2); a2 = fmaf(v2.w, v2.w, a2);
    a3 = fmaf(v3.x, v3.x, a3); a3 = fmaf(v3.y, v3.y, a3); a3 = fmaf(v3.z, v3.z, a3); a3 = fmaf(v3.w, v3.w, a3);
  }
  knorm[j] = (a0 + a1) + (a2 + a3);
}

// ---------------- tiled fp32 GEMM: C = act(A[M,K] @ W[K,N] + bias) ----------------
template <int ACT>
__global__ __launch_bounds__(256) void gemm_kernel(const float* __restrict__ A,
                                                   const float* __restrict__ W,
                                                   const float* __restrict__ bias,
                                                   float* __restrict__ C,
                                                   int M, int N, int K) {
  __shared__ float As[16][68];  // [k][row]
  __shared__ float Bs[16][68];  // [k][col]
  const int tid = threadIdx.x;
  const int tx = tid & 15, ty = tid >> 4;
  const int ar = tid >> 2, ac = tid & 3;
  const int br = tid >> 4, bc = tid & 15;
  const int row0 = blockIdx.y * 64, col0 = blockIdx.x * 64;
  float acc[4][4] = {};
  for (int k0 = 0; k0 < K; k0 += 16) {
    float4 a4 = *(const float4*)(A + (size_t)(row0 + ar) * K + k0 + ac * 4);
    float4 b4 = *(const float4*)(W + (size_t)(k0 + br) * N + col0 + bc * 4);
    __syncthreads();
    As[ac * 4 + 0][ar] = a4.x;
    As[ac * 4 + 1][ar] = a4.y;
    As[ac * 4 + 2][ar] = a4.z;
    As[ac * 4 + 3][ar] = a4.w;
    *(float4*)(&Bs[br][bc * 4]) = b4;
    __syncthreads();
#pragma unroll
    for (int kk = 0; kk < 16; ++kk) {
      float4 av = *(const float4*)(&As[kk][ty * 4]);
      float4 bv = *(const float4*)(&Bs[kk][tx * 4]);
      float ar_[4] = {av.x, av.y, av.z, av.w};
      float br_[4] = {bv.x, bv.y, bv.z, bv.w};
#pragma unroll
      for (int i = 0; i < 4; ++i)
#pragma unroll
        for (int j = 0; j < 4; ++j) acc[i][j] = fmaf(ar_[i], br_[j], acc[i][j]);
    }
  }
  float bb[4];
#pragma unroll
  for (int j = 0; j < 4; ++j) bb[j] = bias[col0 + tx * 4 + j];
#pragma unroll
  for (int i = 0; i < 4; ++i) {
    float4 o;
    float v0 = acc[i][0] + bb[0];
    float v1 = acc[i][1] + bb[1];
    float v2 = acc[i][2] + bb[2];
    float v3 = acc[i][3] + bb[3];
    if (ACT) { v0 = gelu_f(v0); v1 = gelu_f(v1); v2 = gelu_f(v2); v3 = gelu_f(v3); }
    o.x = v0; o.y = v1; o.z = v2; o.w = v3;
    *(float4*)(C + (size_t)(row0 + ty * 4 + i) * N + col0 + tx * 4) = o;
  }
}

// ---------------- distance scan + per-chunk top-8 ----------------
// grid = (256 chunks, 2 query-tiles), block = 256 (thread = query)
__global__ __launch_bounds__(256) void dist_topk_kernel(const float* __restrict__ qc,
                                                        const float* __restrict__ keys,
                                                        const float* __restrict__ knorm,
                                                        u64* __restrict__ cand) {
  const int NKEYS = 100000, CK = 391, NCH = 256;
  const int q = blockIdx.y * 256 + threadIdx.x;
  float4 qv[16];
  const float4* qp = (const float4*)(qc + (size_t)q * 64);
  float qn = 0.f;
#pragma unroll
  for (int i = 0; i < 16; ++i) {
    qv[i] = qp[i];
    qn = fmaf(qv[i].x, qv[i].x, fmaf(qv[i].y, qv[i].y, fmaf(qv[i].z, qv[i].z, fmaf(qv[i].w, qv[i].w, qn))));
  }
  u64 t[8];
#pragma unroll
  for (int i = 0; i < 8; ++i) t[i] = ~0ull;
  const int c0 = blockIdx.x * CK;
  const int c1 = (c0 + CK < NKEYS) ? c0 + CK : NKEYS;
  for (int j = c0; j < c1; ++j) {
    const float4* kr = (const float4*)(keys + (size_t)j * 64);
    float a0 = 0.f, a1 = 0.f, a2 = 0.f, a3 = 0.f;
#pragma unroll
    for (int u = 0; u < 16; u += 4) {
      float4 k0 = kr[u], k1 = kr[u + 1], k2 = kr[u + 2], k3 = kr[u + 3];
      a0 = fmaf(qv[u].x, k0.x, a0);     a0 = fmaf(qv[u].y, k0.y, a0);
      a0 = fmaf(qv[u].z, k0.z, a0);     a0 = fmaf(qv[u].w, k0.w, a0);
      a1 = fmaf(qv[u + 1].x, k1.x, a1); a1 = fmaf(qv[u + 1].y, k1.y, a1);
      a1 = fmaf(qv[u + 1].z, k1.z, a1); a1 = fmaf(qv[u + 1].w, k1.w, a1);
      a2 = fmaf(qv[u + 2].x, k2.x, a2); a2 = fmaf(qv[u + 2].y, k2.y, a2);
      a2 = fmaf(qv[u + 2].z, k2.z, a2); a2 = fmaf(qv[u + 2].w, k2.w, a2);
      a3 = fmaf(qv[u + 3].x, k3.x, a3); a3 = fmaf(qv[u + 3].y, k3.y, a3);
      a3 = fmaf(qv[u + 3].z, k3.z, a3); a3 = fmaf(qv[u + 3].w, k3.w, a3);
    }
    float dot = (a0 + a1) + (a2 + a3);
    float d2v = fmaf(-2.f, dot, qn + knorm[j]);
    d2v = fmaxf(d2v, 0.f);
    u64 c = ((u64)__float_as_uint(d2v) << 32) | (unsigned)j;
    if (c < t[7]) {
      t[7] = c;
      ce64(t[6], t[7]); ce64(t[5], t[6]); ce64(t[4], t[5]); ce64(t[3], t[4]);
      ce64(t[2], t[3]); ce64(t[1], t[2]); ce64(t[0], t[1]);
    }
  }
  u64* cp = cand + ((size_t)q * NCH + blockIdx.x) * 8;
#pragma unroll
  for (int i = 0; i < 8; ++i) cp[i] = t[i];
}

// ---------------- merge 256 chunk-lists -> final top-8, weights, confidence ----------------
__global__ __launch_bounds__(256) void topk_merge_kernel(const u64* __restrict__ cand,
                                                         int* __restrict__ idxb,
                                                         float* __restrict__ wtsb,
                                                         float* __restrict__ conf) {
  const int q = blockIdx.x, tid = threadIdx.x;
  u64 t[8];
  const u64* cp = cand + ((size_t)q * 256 + tid) * 8;
#pragma unroll
  for (int i = 0; i < 8; ++i) t[i] = cp[i];
#pragma unroll
  for (int m = 1; m < 64; m <<= 1) {
    u64 o[8];
#pragma unroll
    for (int i = 0; i < 8; ++i) o[i] = shflx64(t[i], m);
    take8(t, o);
  }
  __shared__ u64 sh[3][8];
  const int wv = tid >> 6, lane = tid & 63;
  if (wv > 0 && lane == 0) {
#pragma unroll
    for (int i = 0; i < 8; ++i) sh[wv - 1][i] = t[i];
  }
  __syncthreads();
  if (wv == 0) {
#pragma unroll
    for (int w = 0; w < 3; ++w) {
      u64 o[8];
#pragma unroll
      for (int i = 0; i < 8; ++i) o[i] = sh[w][i];
      take8(t, o);
    }
    if (lane == 0) {
      float w8[8], s = 0.f;
#pragma unroll
      for (int i = 0; i < 8; ++i) {
        float d = __uint_as_float((unsigned)(t[i] >> 32));
        w8[i] = 1.f / (d + 1e-6f);
        s += w8[i];
      }
      conf[q] = w8[0];
#pragma unroll
      for (int i = 0; i < 8; ++i) {
        idxb[q * 8 + i] = (int)(unsigned)(t[i] & 0xffffffffull);
        wtsb[q * 8 + i] = w8[i] / s;
      }
    }
  }
}

// ---------------- gather: dec_in[r] = [keys[idx[r]] (64) , context[r>>3] (1024)] ----------------
__global__ __launch_bounds__(256) void gather_kernel(const float* __restrict__ keys,
                                                     const float* __restrict__ context,
                                                     const int* __restrict__ idxb,
                                                     float* __restrict__ decin) {
  const int r = blockIdx.x;
  const int b = r >> 3;
  const int id = idxb[r];
  const float4* kp = (const float4*)(keys + (size_t)id * 64);
  const float4* cp = (const float4*)(context + (size_t)b * 1024);
  float4* op = (float4*)(decin + (size_t)r * 1088);
  for (int c = threadIdx.x; c < 272; c += 256) {
    float4 v = (c < 16) ? kp[c] : cp[c - 16];
    op[c] = v;
  }
}

// ---------------- weighted combine ----------------
__global__ __launch_bounds__(256) void combine_kernel(const float* __restrict__ dec,
                                                      const float* __restrict__ wtsb,
                                                      float* __restrict__ out) {
  const int b = blockIdx.x, tid = threadIdx.x;
  float w[8];
#pragma unroll
  for (int i = 0; i < 8; ++i) w[i] = wtsb[b * 8 + i];
  const float4* d4 = (const float4*)(dec + (size_t)b * 8192);
  float4 acc = {0.f, 0.f, 0.f, 0.f};
#pragma unroll
  for (int i = 0; i < 8; ++i) {
    float4 v = d4[(size_t)i * 256 + tid];
    acc.x = fmaf(w[i], v.x, acc.x);
    acc.y = fmaf(w[i], v.y, acc.y);
    acc.z = fmaf(w[i], v.z, acc.z);
    acc.w = fmaf(w[i], v.w, acc.w);
  }
  ((float4*)out)[(size_t)b * 256 + tid] = acc;
}

extern "C" void kernel_launch(void* const* d_in, const int* in_sizes, int n_in,
                              void* d_out, int out_size, void* d_ws, size_t ws_size,
                              hipStream_t stream) {
  const float* query   = (const float*)d_in[0];
  const float* context = (const float*)d_in[1];
  const float* keys    = (const float*)d_in[2];
  const float* ew1 = (const float*)d_in[3];
  const float* eb1 = (const float*)d_in[4];
  const float* ew2 = (const float*)d_in[5];
  const float* eb2 = (const float*)d_in[6];
  const float* ew3 = (const float*)d_in[7];
  const float* eb3 = (const float*)d_in[8];
  const float* dw1 = (const float*)d_in[9];
  const float* db1 = (const float*)d_in[10];
  const float* dw2 = (const float*)d_in[11];
  const float* db2 = (const float*)d_in[12];
  const float* dw3 = (const float*)d_in[13];
  const float* db3 = (const float*)d_in[14];
  float* out = (float*)d_out;

  char* ws = (char*)d_ws;
  float* qc    = (float*)(ws + 0);          // 512*64*4      = 131072
  float* knorm = (float*)(ws + 131072);     // 100000*4      = 400000
  float* eh1   = (float*)(ws + 531200);     // 512*256*4     = 524288
  float* eh2   = (float*)(ws + 1055488);    // 512*128*4     = 262144
  int*   idxb  = (int*)  (ws + 1317632);    // 4096*4        = 16384
  float* wtsb  = (float*)(ws + 1334016);    // 4096*4        = 16384
  u64*   cand  = (u64*)  (ws + 1350400);    // 512*256*8*8   = 8388608
  float* decin = (float*)(ws + 1350400);    // 4096*1088*4   = 17825792 (aliases cand; cand dead by then)
  float* h1d   = (float*)(ws + 19176192);   // 4096*256*4    = 4194304
  float* h2d   = (float*)(ws + 23370496);   // 4096*512*4    = 8388608
  float* dec   = (float*)(ws + 31759104);   // 4096*1024*4   = 16777216  (end: 48536320)

  // key norms (keys reused later; 25.6MB -> L3 resident)
  knorm_kernel<<<dim3(391), dim3(256), 0, stream>>>(keys, knorm);

  // encoder: q -> qc [512,64]
  gemm_kernel<1><<<dim3(4, 8),  dim3(256), 0, stream>>>(query, ew1, eb1, eh1, 512, 256, 1024);
  gemm_kernel<1><<<dim3(2, 8),  dim3(256), 0, stream>>>(eh1,   ew2, eb2, eh2, 512, 128, 256);
  gemm_kernel<0><<<dim3(1, 8),  dim3(256), 0, stream>>>(eh2,   ew3, eb3, qc,  512, 64,  128);

  // distance scan + per-chunk top8, then merge
  dist_topk_kernel<<<dim3(256, 2), dim3(256), 0, stream>>>(qc, keys, knorm, cand);
  topk_merge_kernel<<<dim3(512), dim3(256), 0, stream>>>(cand, idxb, wtsb, out + 524288);

  // decode
  gather_kernel<<<dim3(4096), dim3(256), 0, stream>>>(keys, context, idxb, decin);
  gemm_kernel<1><<<dim3(4, 64),  dim3(256), 0, stream>>>(decin, dw1, db1, h1d, 4096, 256,  1088);
  gemm_kernel<1><<<dim3(8, 64),  dim3(256), 0, stream>>>(h1d,   dw2, db2, h2d, 4096, 512,  256);
  gemm_kernel<0><<<dim3(16, 64), dim3(256), 0, stream>>>(h2d,   dw3, db3, dec, 4096, 1024, 512);

  // weighted combine -> out[0 .. 512*1024)
  combine_kernel<<<dim3(512), dim3(256), 0, stream>>>(dec, wtsb, out);
}

// Round 2
// 424.413 us; speedup vs baseline: 1.2632x; 1.2632x over previous
//
#include <hip/hip_runtime.h>

typedef unsigned long long u64;

#define DEVI __device__ __forceinline__

DEVI float gelu_f(float x) { return 0.5f * x * (1.0f + erff(x * 0.70710678f)); }

DEVI void ce64(u64& a, u64& b) { u64 lo = a < b ? a : b; u64 hi = a < b ? b : a; a = lo; b = hi; }

DEVI u64 shflx64(u64 v, int m) {
  unsigned lo = (unsigned)__shfl_xor((int)(v & 0xffffffffull), m, 64);
  unsigned hi = (unsigned)__shfl_xor((int)(v >> 32), m, 64);
  return ((u64)hi << 32) | lo;
}

// t, o both sorted ascending; t <- smallest 8 of union, sorted ascending.
DEVI void take8(u64 t[8], const u64 o[8]) {
  u64 s[8];
#pragma unroll
  for (int i = 0; i < 8; ++i) { u64 x = o[7 - i]; s[i] = (t[i] < x) ? t[i] : x; }
  ce64(s[0], s[4]); ce64(s[1], s[5]); ce64(s[2], s[6]); ce64(s[3], s[7]);
  ce64(s[0], s[2]); ce64(s[1], s[3]); ce64(s[4], s[6]); ce64(s[5], s[7]);
  ce64(s[0], s[1]); ce64(s[2], s[3]); ce64(s[4], s[5]); ce64(s[6], s[7]);
#pragma unroll
  for (int i = 0; i < 8; ++i) t[i] = s[i];
}

// ---------------- key norms ----------------
__global__ __launch_bounds__(256) void knorm_kernel(const float* __restrict__ keys,
                                                    float* __restrict__ knorm) {
  int j = blockIdx.x * 256 + threadIdx.x;
  if (j >= 100000) return;
  const float4* kp = (const float4*)(keys + (size_t)j * 64);
  float a0 = 0.f, a1 = 0.f, a2 = 0.f, a3 = 0.f;
#pragma unroll
  for (int u = 0; u < 16; u += 4) {
    float4 v0 = kp[u], v1 = kp[u + 1], v2 = kp[u + 2], v3 = kp[u + 3];
    a0 = fmaf(v0.x, v0.x, a0); a0 = fmaf(v0.y, v0.y, a0); a0 = fmaf(v0.z, v0.z, a0); a0 = fmaf(v0.w, v0.w, a0);
    a1 = fmaf(v1.x, v1.x, a1); a1 = fmaf(v1.y, v1.y, a1); a1 = fmaf(v1.z, v1.z, a1); a1 = fmaf(v1.w, v1.w, a1);
    a2 = fmaf(v2.x, v2.x, a2); a2 = fmaf(v2.y, v2.y, a2); a2 = fmaf(v2.z, v2.z, a2); a2 = fmaf(v2.w, v2.w, a2);
    a3 = fmaf(v3.x, v3.x, a3); a3 = fmaf(v3.y, v3.y, a3); a3 = fmaf(v3.z, v3.z, a3); a3 = fmaf(v3.w, v3.w, a3);
  }
  knorm[j] = (a0 + a1) + (a2 + a3);
}

// ---------------- tiled fp32 GEMM: C = act(A[M,K] @ W[K,N] + bias) ----------------
template <int ACT, int BIAS>
__global__ __launch_bounds__(256) void gemm_kernel(const float* __restrict__ A,
                                                   const float* __restrict__ W,
                                                   const float* __restrict__ bias,
                                                   float* __restrict__ C,
                                                   int M, int N, int K) {
  __shared__ float As[16][68];  // [k][row]
  __shared__ float Bs[16][68];  // [k][col]
  const int tid = threadIdx.x;
  const int tx = tid & 15, ty = tid >> 4;
  const int ar = tid >> 2, ac = tid & 3;
  const int br = tid >> 4, bc = tid & 15;
  const int row0 = blockIdx.y * 64, col0 = blockIdx.x * 64;
  float acc[4][4] = {};
  for (int k0 = 0; k0 < K; k0 += 16) {
    float4 a4 = *(const float4*)(A + (size_t)(row0 + ar) * K + k0 + ac * 4);
    float4 b4 = *(const float4*)(W + (size_t)(k0 + br) * N + col0 + bc * 4);
    __syncthreads();
    As[ac * 4 + 0][ar] = a4.x;
    As[ac * 4 + 1][ar] = a4.y;
    As[ac * 4 + 2][ar] = a4.z;
    As[ac * 4 + 3][ar] = a4.w;
    *(float4*)(&Bs[br][bc * 4]) = b4;
    __syncthreads();
#pragma unroll
    for (int kk = 0; kk < 16; ++kk) {
      float4 av = *(const float4*)(&As[kk][ty * 4]);
      float4 bv = *(const float4*)(&Bs[kk][tx * 4]);
      float ar_[4] = {av.x, av.y, av.z, av.w};
      float br_[4] = {bv.x, bv.y, bv.z, bv.w};
#pragma unroll
      for (int i = 0; i < 4; ++i)
#pragma unroll
        for (int j = 0; j < 4; ++j) acc[i][j] = fmaf(ar_[i], br_[j], acc[i][j]);
    }
  }
  float bb[4] = {0.f, 0.f, 0.f, 0.f};
  if (BIAS) {
#pragma unroll
    for (int j = 0; j < 4; ++j) bb[j] = bias[col0 + tx * 4 + j];
  }
#pragma unroll
  for (int i = 0; i < 4; ++i) {
    float4 o;
    float v0 = acc[i][0] + bb[0];
    float v1 = acc[i][1] + bb[1];
    float v2 = acc[i][2] + bb[2];
    float v3 = acc[i][3] + bb[3];
    if (ACT) { v0 = gelu_f(v0); v1 = gelu_f(v1); v2 = gelu_f(v2); v3 = gelu_f(v3); }
    o.x = v0; o.y = v1; o.z = v2; o.w = v3;
    *(float4*)(C + (size_t)(row0 + ty * 4 + i) * N + col0 + tx * 4) = o;
  }
}

// ---------------- distance scan + per-chunk top-8 ----------------
// grid = (512 chunks, 2 query-tiles), block = 256 (thread = query)
__global__ __launch_bounds__(256, 4) void dist_topk_kernel(const float* __restrict__ qc,
                                                           const float* __restrict__ keys,
                                                           const float* __restrict__ knorm,
                                                           u64* __restrict__ cand) {
  const int NKEYS = 100000, CK = 196, NCH = 512;
  const int q = blockIdx.y * 256 + threadIdx.x;
  float4 qv[16];
  const float4* qp = (const float4*)(qc + (size_t)q * 64);
  float qn = 0.f;
#pragma unroll
  for (int i = 0; i < 16; ++i) {
    qv[i] = qp[i];
    qn = fmaf(qv[i].x, qv[i].x, fmaf(qv[i].y, qv[i].y, fmaf(qv[i].z, qv[i].z, fmaf(qv[i].w, qv[i].w, qn))));
  }
  u64 t[8];
#pragma unroll
  for (int i = 0; i < 8; ++i) t[i] = ~0ull;
  const int c0 = blockIdx.x * CK;
  const int c1 = (c0 + CK < NKEYS) ? c0 + CK : NKEYS;
  for (int j = c0; j < c1; ++j) {
    const float4* kr = (const float4*)(keys + (size_t)j * 64);
    float a0 = 0.f, a1 = 0.f, a2 = 0.f, a3 = 0.f;
#pragma unroll
    for (int u = 0; u < 16; u += 4) {
      float4 k0 = kr[u], k1 = kr[u + 1], k2 = kr[u + 2], k3 = kr[u + 3];
      a0 = fmaf(qv[u].x, k0.x, a0);     a0 = fmaf(qv[u].y, k0.y, a0);
      a0 = fmaf(qv[u].z, k0.z, a0);     a0 = fmaf(qv[u].w, k0.w, a0);
      a1 = fmaf(qv[u + 1].x, k1.x, a1); a1 = fmaf(qv[u + 1].y, k1.y, a1);
      a1 = fmaf(qv[u + 1].z, k1.z, a1); a1 = fmaf(qv[u + 1].w, k1.w, a1);
      a2 = fmaf(qv[u + 2].x, k2.x, a2); a2 = fmaf(qv[u + 2].y, k2.y, a2);
      a2 = fmaf(qv[u + 2].z, k2.z, a2); a2 = fmaf(qv[u + 2].w, k2.w, a2);
      a3 = fmaf(qv[u + 3].x, k3.x, a3); a3 = fmaf(qv[u + 3].y, k3.y, a3);
      a3 = fmaf(qv[u + 3].z, k3.z, a3); a3 = fmaf(qv[u + 3].w, k3.w, a3);
    }
    float dot = (a0 + a1) + (a2 + a3);
    float d2v = fmaf(-2.f, dot, qn + knorm[j]);
    d2v = fmaxf(d2v, 0.f);
    u64 c = ((u64)__float_as_uint(d2v) << 32) | (unsigned)j;
    if (c < t[7]) {
      t[7] = c;
      ce64(t[6], t[7]); ce64(t[5], t[6]); ce64(t[4], t[5]); ce64(t[3], t[4]);
      ce64(t[2], t[3]); ce64(t[1], t[2]); ce64(t[0], t[1]);
    }
  }
  u64* cp = cand + ((size_t)q * NCH + blockIdx.x) * 8;
#pragma unroll
  for (int i = 0; i < 8; ++i) cp[i] = t[i];
}

// ---------------- merge 512 chunk-lists -> final top-8, weights, confidence ----------------
__global__ __launch_bounds__(256) void topk_merge_kernel(const u64* __restrict__ cand,
                                                         int* __restrict__ idxb,
                                                         float* __restrict__ wtsb,
                                                         float* __restrict__ conf) {
  const int q = blockIdx.x, tid = threadIdx.x;
  u64 t[8], o[8];
  const u64* cp = cand + ((size_t)q * 512 + (size_t)tid * 2) * 8;
#pragma unroll
  for (int i = 0; i < 8; ++i) t[i] = cp[i];
#pragma unroll
  for (int i = 0; i < 8; ++i) o[i] = cp[8 + i];
  take8(t, o);
#pragma unroll
  for (int m = 1; m < 64; m <<= 1) {
    u64 o2[8];
#pragma unroll
    for (int i = 0; i < 8; ++i) o2[i] = shflx64(t[i], m);
    take8(t, o2);
  }
  __shared__ u64 sh[3][8];
  const int wv = tid >> 6, lane = tid & 63;
  if (wv > 0 && lane == 0) {
#pragma unroll
    for (int i = 0; i < 8; ++i) sh[wv - 1][i] = t[i];
  }
  __syncthreads();
  if (wv == 0) {
#pragma unroll
    for (int w = 0; w < 3; ++w) {
      u64 o2[8];
#pragma unroll
      for (int i = 0; i < 8; ++i) o2[i] = sh[w][i];
      take8(t, o2);
    }
    if (lane == 0) {
      float w8[8], s = 0.f;
#pragma unroll
      for (int i = 0; i < 8; ++i) {
        float d = __uint_as_float((unsigned)(t[i] >> 32));
        w8[i] = 1.f / (d + 1e-6f);
        s += w8[i];
      }
      conf[q] = w8[0];
#pragma unroll
      for (int i = 0; i < 8; ++i) {
        idxb[q * 8 + i] = (int)(unsigned)(t[i] & 0xffffffffull);
        wtsb[q * 8 + i] = w8[i] / s;
      }
    }
  }
}

// ---------------- decoder layer 1, fused gather + skinny GEMM ----------------
// h1d[r,:] = gelu( keys[idx[r]] @ dw1[0:64,:] + h1c[r>>3,:] + db1 )
// grid = (256/64, 4096/64), block = 256
__global__ __launch_bounds__(256) void dec1_kernel(const float* __restrict__ keys,
                                                   const int* __restrict__ idxb,
                                                   const float* __restrict__ h1c,
                                                   const float* __restrict__ dw1,
                                                   const float* __restrict__ db1,
                                                   float* __restrict__ h1d) {
  __shared__ float As[64][68];  // [k][row]
  __shared__ float Bs[64][68];  // [k][col]
  const int tid = threadIdx.x;
  const int tx = tid & 15, ty = tid >> 4;
  const int r0 = blockIdx.y * 64, c0 = blockIdx.x * 64;
  // gather 64 key rows, transposed
  {
    const int row = tid >> 2, qd = tid & 3;
    const int id = idxb[r0 + row];
    const float4* kp = (const float4*)(keys + (size_t)id * 64 + qd * 16);
#pragma unroll
    for (int u = 0; u < 4; ++u) {
      float4 v = kp[u];
      As[qd * 16 + u * 4 + 0][row] = v.x;
      As[qd * 16 + u * 4 + 1][row] = v.y;
      As[qd * 16 + u * 4 + 2][row] = v.z;
      As[qd * 16 + u * 4 + 3][row] = v.w;
    }
  }
  // load dw1[0:64][c0:c0+64]
  {
    const int brr = tid >> 4, bcc = tid & 15;
#pragma unroll
    for (int p = 0; p < 4; ++p) {
      float4 v = *(const float4*)(dw1 + (size_t)(p * 16 + brr) * 256 + c0 + bcc * 4);
      *(float4*)(&Bs[p * 16 + brr][bcc * 4]) = v;
    }
  }
  __syncthreads();
  float acc[4][4] = {};
#pragma unroll
  for (int kk = 0; kk < 64; ++kk) {
    float4 av = *(const float4*)(&As[kk][ty * 4]);
    float4 bv = *(const float4*)(&Bs[kk][tx * 4]);
    float ar_[4] = {av.x, av.y, av.z, av.w};
    float br_[4] = {bv.x, bv.y, bv.z, bv.w};
#pragma unroll
    for (int i = 0; i < 4; ++i)
#pragma unroll
      for (int j = 0; j < 4; ++j) acc[i][j] = fmaf(ar_[i], br_[j], acc[i][j]);
  }
  float bb[4];
#pragma unroll
  for (int j = 0; j < 4; ++j) bb[j] = db1[c0 + tx * 4 + j];
#pragma unroll
  for (int i = 0; i < 4; ++i) {
    const int row = r0 + ty * 4 + i;
    const float4 hv = *(const float4*)(h1c + (size_t)(row >> 3) * 256 + c0 + tx * 4);
    float4 o;
    o.x = gelu_f(acc[i][0] + hv.x + bb[0]);
    o.y = gelu_f(acc[i][1] + hv.y + bb[1]);
    o.z = gelu_f(acc[i][2] + hv.z + bb[2]);
    o.w = gelu_f(acc[i][3] + hv.w + bb[3]);
    *(float4*)(h1d + (size_t)row * 256 + c0 + tx * 4) = o;
  }
}

// ---------------- weighted combine ----------------
__global__ __launch_bounds__(256) void combine_kernel(const float* __restrict__ dec,
                                                      const float* __restrict__ wtsb,
                                                      float* __restrict__ out) {
  const int b = blockIdx.x, tid = threadIdx.x;
  float w[8];
#pragma unroll
  for (int i = 0; i < 8; ++i) w[i] = wtsb[b * 8 + i];
  const float4* d4 = (const float4*)(dec + (size_t)b * 8192);
  float4 acc = {0.f, 0.f, 0.f, 0.f};
#pragma unroll
  for (int i = 0; i < 8; ++i) {
    float4 v = d4[(size_t)i * 256 + tid];
    acc.x = fmaf(w[i], v.x, acc.x);
    acc.y = fmaf(w[i], v.y, acc.y);
    acc.z = fmaf(w[i], v.z, acc.z);
    acc.w = fmaf(w[i], v.w, acc.w);
  }
  ((float4*)out)[(size_t)b * 256 + tid] = acc;
}

extern "C" void kernel_launch(void* const* d_in, const int* in_sizes, int n_in,
                              void* d_out, int out_size, void* d_ws, size_t ws_size,
                              hipStream_t stream) {
  const float* query   = (const float*)d_in[0];
  const float* context = (const float*)d_in[1];
  const float* keys    = (const float*)d_in[2];
  const float* ew1 = (const float*)d_in[3];
  const float* eb1 = (const float*)d_in[4];
  const float* ew2 = (const float*)d_in[5];
  const float* eb2 = (const float*)d_in[6];
  const float* ew3 = (const float*)d_in[7];
  const float* eb3 = (const float*)d_in[8];
  const float* dw1 = (const float*)d_in[9];
  const float* db1 = (const float*)d_in[10];
  const float* dw2 = (const float*)d_in[11];
  const float* db2 = (const float*)d_in[12];
  const float* dw3 = (const float*)d_in[13];
  const float* db3 = (const float*)d_in[14];
  float* out = (float*)d_out;

  char* ws = (char*)d_ws;
  float* qc    = (float*)(ws + 0);          // 512*64*4       = 131072
  float* knorm = (float*)(ws + 131072);     // 100000*4       = 400000
  float* eh1   = (float*)(ws + 531200);     // 512*256*4      = 524288
  float* eh2   = (float*)(ws + 1055488);    // 512*128*4      = 262144
  int*   idxb  = (int*)  (ws + 1317632);    // 4096*4         = 16384
  float* wtsb  = (float*)(ws + 1334016);    // 4096*4         = 16384
  float* h1c   = (float*)(ws + 1350400);    // 512*256*4      = 524288
  u64*   cand  = (u64*)  (ws + 1874688);    // 512*512*8*8    = 16777216
  float* h1d   = (float*)(ws + 18651904);   // 4096*256*4     = 4194304
  float* h2d   = (float*)(ws + 22846208);   // 4096*512*4     = 8388608
  float* dec   = (float*)(ws + 31234816);   // 4096*1024*4    = 16777216  (end: 48012032)

  // key norms (keys reused later; 25.6MB -> L2/L3 resident)
  knorm_kernel<<<dim3(391), dim3(256), 0, stream>>>(keys, knorm);

  // encoder: q -> qc [512,64]
  gemm_kernel<1, 1><<<dim3(4, 8), dim3(256), 0, stream>>>(query, ew1, eb1, eh1, 512, 256, 1024);
  gemm_kernel<1, 1><<<dim3(2, 8), dim3(256), 0, stream>>>(eh1,   ew2, eb2, eh2, 512, 128, 256);
  gemm_kernel<0, 1><<<dim3(1, 8), dim3(256), 0, stream>>>(eh2,   ew3, eb3, qc,  512, 64,  128);

  // shared context part of decoder layer 1: h1c = context @ dw1[64:,:]
  gemm_kernel<0, 0><<<dim3(4, 8), dim3(256), 0, stream>>>(context, dw1 + (size_t)64 * 256, nullptr,
                                                          h1c, 512, 256, 1024);

  // distance scan + per-chunk top8, then merge
  dist_topk_kernel<<<dim3(512, 2), dim3(256), 0, stream>>>(qc, keys, knorm, cand);
  topk_merge_kernel<<<dim3(512), dim3(256), 0, stream>>>(cand, idxb, wtsb, out + 524288);

  // decoder layer 1 (fused gather + K=64 GEMM + shared-context add)
  dec1_kernel<<<dim3(4, 64), dim3(256), 0, stream>>>(keys, idxb, h1c, dw1, db1, h1d);

  // decoder layers 2,3
  gemm_kernel<1, 1><<<dim3(8, 64),  dim3(256), 0, stream>>>(h1d, dw2, db2, h2d, 4096, 512,  256);
  gemm_kernel<0, 1><<<dim3(16, 64), dim3(256), 0, stream>>>(h2d, dw3, db3, dec, 4096, 1024, 512);

  // weighted combine -> out[0 .. 512*1024)
  combine_kernel<<<dim3(512), dim3(256), 0, stream>>>(dec, wtsb, out);
}